// Round 10
// baseline (1729.711 us; speedup 1.0000x reference)
//
#include <hip/hip_runtime.h>

// LSTM (B=256, T=256, F=128, H=1024) + sigmoid + FC(1024->128).
// Persistent 256-WG x 256-thread kernel (4 waves, 1 wave/SIMD: W-in-regs needs
// the full per-wave VGPR budget; R9 proved 8 waves forces W out of registers).
// Per step t: gates[32rows x 128cols] = [h|x](fp16) x W_cat^T(fp16, register-
// resident) + bias; per-lane i,f,g,o -> c,h update (fp32).
//
// R10: h exchanged in MFMA A-FRAGMENT LAYOUT at the MALL (agent-scope relaxed
// atomics, proven R3/R5/R7/R8 coherence; NO cache-wide maintenance ops):
//   hb[buf][rg][chunk 0..63][lane 0..63][16B], chunk = 16 k-cols x 32 rows:
//   byte(chunk,l,j) = h[row=l&31][col = chunk*16 + (l>>5)*8 + j]
// Consumers load fragments DIRECTLY to registers (rolling 4-deep, two u64
// agent loads per 1KB chunk, fully coalesced) -> the R8 LDS stage round trip
// (stage writes + lgkmcnt + ds_read_b128 frag reads) is deleted.
// Producers write their 32x32 tile as 2 contiguous 1KB chunks: 256 threads x
// one coalesced 8B agent store, sourced from the 2KB hst LDS tile.
// Wave w consumes h chunks [16w,16w+16) (K [w*256,+256)) + x-K [w*32,+32).
// Reduce: 4-wave, separate 64KB LDS buffer (R8). Cell: 4 rows/thread (R8).
// Barrier: RMW-free epoch flags; wave w polls its 8 producers cg' in
// [8w,8w+8). 4 rotating h buffers; transitivity: flag[p]=t => p passed
// poll(t-2) => all 32 flags >= t-1 => all reads of h(t-3) done => writing
// hb[(t+1)&3] safe. Monotonic flags, replay-safe.
// MFMA mfma_f32_32x32x16_f16: A lane row=l&31,k=(l>>5)*8+j; B col=l&31,
// same k; C col=l&31, row=(reg&3)+8*(reg>>2)+4*(l>>5) [m101].

typedef _Float16 f16x8 __attribute__((ext_vector_type(8)));
typedef float f32x16 __attribute__((ext_vector_type(16)));
typedef unsigned long long u64;
struct U128 { u64 a, b; };

#define SCOPE_AGENT __HIP_MEMORY_SCOPE_AGENT

#define WS_WP    0ull
#define WS_BIAS  9437184ull
#define WS_XT    (WS_BIAS + 16384ull)
#define WS_HB    (WS_XT + 16777216ull)          // 4 buffers x 524288B
#define WS_SIGH  (WS_HB + 4ull * 524288ull)
#define WS_BAR   (WS_SIGH + 1048576ull)

__device__ __forceinline__ unsigned short f2h(float f) {
  _Float16 h = (_Float16)f;
  return __builtin_bit_cast(unsigned short, h);
}

__device__ __forceinline__ float fast_sig(float x) {
  return __builtin_amdgcn_rcpf(1.f + __expf(-x));
}
__device__ __forceinline__ float fast_tanh(float x) {
  return __builtin_fmaf(2.f, fast_sig(2.f * x), -1.f);
}

// Agent-coherent 16B fragment load (two u64 relaxed atomics -> MALL).
__device__ __forceinline__ int4 load_frag(const char* p) {
  U128 u;
  u.a = __hip_atomic_load((const u64*)p,       __ATOMIC_RELAXED, SCOPE_AGENT);
  u.b = __hip_atomic_load((const u64*)(p + 8), __ATOMIC_RELAXED, SCOPE_AGENT);
  return __builtin_bit_cast(int4, u);
}

// Pack W_cat[4096][1152] (fp16) into per-(cg,wave,n,q,lane) MFMA B-fragments.
// flat idx i = ((((cg*4 + w)*4 + n)*18 + q)*64 + l)*8 + j
//   gcol = n*1024 + cg*32 + (l&31); khi = (l>>5)*8 + j
//   q<16:  k = w*256 + q*16 + khi  (h region, W_hh[gcol][k])
//   q>=16: f = w*32 + (q-16)*16 + khi  (x region, W_ih[gcol][f])
__global__ void prep_pack(const float* __restrict__ W_ih, const float* __restrict__ W_hh,
                          const float* __restrict__ b_ih, const float* __restrict__ b_hh,
                          unsigned short* __restrict__ wp, float* __restrict__ bias) {
  unsigned i = blockIdx.x * 256u + threadIdx.x;
  if (i < 4718592u) {
    unsigned j = i & 7u;
    unsigned l = (i >> 3) & 63u;
    unsigned rest = i >> 9;
    unsigned q = rest % 18u;
    unsigned rest2 = rest / 18u;
    unsigned n = rest2 & 3u;
    unsigned rest3 = rest2 >> 2;
    unsigned w = rest3 & 3u;
    unsigned cg = rest3 >> 2;
    unsigned gcol = n * 1024u + cg * 32u + (l & 31u);
    unsigned khi = (l >> 5) * 8u + j;
    float v;
    if (q < 16u) {
      unsigned k = w * 256u + q * 16u + khi;
      v = W_hh[(size_t)gcol * 1024u + k];
    } else {
      unsigned k = w * 32u + (q - 16u) * 16u + khi;
      v = W_ih[(size_t)gcol * 128u + k];
    }
    wp[i] = f2h(v);
  }
  if (i < 4096u) bias[i] = b_ih[i] + b_hh[i];
}

// x[B][T][F] fp32 -> xT[T][B][F] fp16 ; h0 -> hb buffer 0 in FRAGMENT layout;
// zero flags.
__global__ void prep_misc(const float* __restrict__ x, const float* __restrict__ h0,
                          unsigned short* __restrict__ xT, unsigned short* __restrict__ hb0,
                          unsigned* __restrict__ bar) {
  unsigned i = blockIdx.x * 256u + threadIdx.x;
  if (i < 8388608u) {
    unsigned f = i & 127u;
    unsigned b = (i >> 7) & 255u;
    unsigned t = i >> 15;
    xT[i] = f2h(x[((size_t)b * 256u + t) * 128u + f]);
  }
  if (i < 262144u) {
    // hb0[rg][chunk][l][j] = h0[rg*32 + (l&31)][chunk*16 + (l>>5)*8 + j]
    unsigned j = i & 7u;
    unsigned l = (i >> 3) & 63u;
    unsigned chunk = (i >> 9) & 63u;
    unsigned rg = i >> 15;
    unsigned row = rg * 32u + (l & 31u);
    unsigned col = chunk * 16u + (l >> 5) * 8u + j;
    hb0[i] = f2h(h0[row * 1024u + col]);
  }
  if (i < 768u) bar[i] = 0u;
}

__launch_bounds__(256, 1)
__global__ void lstm_main(const unsigned short* __restrict__ wp,
                          const float* __restrict__ bias,
                          const unsigned short* __restrict__ xT,
                          unsigned short* __restrict__ hb,
                          const float* __restrict__ c0,
                          float* __restrict__ sigh,
                          unsigned* __restrict__ bar) {
  extern __shared__ char lds[];
  float4* redv = (float4*)lds;                            // 64 KB reduce
  unsigned short* hst = (unsigned short*)(lds + 65536);   // 2 KB h tile

  const unsigned tid = threadIdx.x;
  const unsigned wg  = blockIdx.x;
  const unsigned w   = tid >> 6;       // wave 0..3 (K-slice owner)
  const unsigned l   = tid & 63u;
  const unsigned rg  = wg >> 5;        // 0..7  cohort (32 rows)
  const unsigned cg  = wg & 31u;       // 0..31 col group (32 cols)
  const unsigned lo5 = l & 31u;
  const unsigned hi  = l >> 5;

  // ---- register-resident W fragments (72 x int4 = 288 regs) ----
  int4 Braw[4][18];
  {
    const int4* wpv = (const int4*)wp;
    const unsigned wbase = (cg * 4u + w) * 4608u;
#pragma unroll
    for (int n = 0; n < 4; ++n) {
#pragma unroll
      for (int q = 0; q < 18; ++q) {
        Braw[n][q] = wpv[wbase + (unsigned)(n * 18 + q) * 64u + l];
      }
    }
  }

  float bias_v[4];
#pragma unroll
  for (int n = 0; n < 4; ++n) bias_v[n] = bias[(unsigned)n * 1024u + cg * 32u + lo5];

  // cell rows r = rg*32 + 8w + i + 4*hi, col = cg*32 + lo5
  const unsigned col = cg * 32u + lo5;
  float c_st[4];
  unsigned soff[4];
#pragma unroll
  for (int i = 0; i < 4; ++i) {
    unsigned r = rg * 32u + 8u * w + (unsigned)i + 4u * hi;
    soff[i] = r * 1024u + col;
    c_st[i] = c0[soff[i]];
  }

  // consumer fragment addressing: wave w reads chunks 16w..16w+15
  const unsigned fragbase = rg * 65536u + (w * 16u) * 1024u + l * 16u;
  // x: lane l -> row rg*32+(l&31), f = w*32 + hi*8 ; +65536/step
  unsigned xb = ((rg * 32u + lo5) * 128u + w * 32u + hi * 8u) * 2u;

  const char* xbase = (const char*)xT;
  const char* hbase = (const char*)hb;
  unsigned* flags = &bar[rg * 32u];    // 32 epoch flags, one 128B line

  // producer fragment write: 256 threads x 8B coalesced
  //   pq = chunk half (0/1), pl = dest lane, pp = which 8B of the 16B
  const unsigned pq = tid >> 7;
  const unsigned pl = (tid >> 1) & 63u;
  const unsigned pp = tid & 1u;
  const unsigned plc = pq * 16u + (pl >> 5) * 8u + pp * 4u;   // local col
  const unsigned hst_rd = (pl & 31u) * 64u + plc * 2u;        // byte in hst
  const unsigned pw_off = rg * 65536u + (cg * 2u + pq) * 1024u + pl * 16u + pp * 8u;

  int4 xr[2];
  xr[0] = *(const int4*)(xbase + xb);
  xr[1] = *(const int4*)(xbase + xb + 32u);

  for (unsigned t = 0; t < 256u; ++t) {
    const char* hrd = hbase + ((t & 3u) * 524288u);
    char* hwr = (char*)hbase + (((t + 1u) & 3u) * 524288u);

    // ---- preload first 4 h fragment chunks (direct to registers) ----
    int4 ah[4];
#pragma unroll
    for (int q = 0; q < 4; ++q)
      ah[q] = load_frag(hrd + fragbase + (unsigned)q * 1024u);

    f32x16 acc[4] = {};
    // x chunks (q=16,17) while h loads are in flight
#pragma unroll
    for (int qx = 0; qx < 2; ++qx) {
      f16x8 a = __builtin_bit_cast(f16x8, xr[qx]);
      acc[0] = __builtin_amdgcn_mfma_f32_32x32x16_f16(a, __builtin_bit_cast(f16x8, Braw[0][16 + qx]), acc[0], 0, 0, 0);
      acc[1] = __builtin_amdgcn_mfma_f32_32x32x16_f16(a, __builtin_bit_cast(f16x8, Braw[1][16 + qx]), acc[1], 0, 0, 0);
      acc[2] = __builtin_amdgcn_mfma_f32_32x32x16_f16(a, __builtin_bit_cast(f16x8, Braw[2][16 + qx]), acc[2], 0, 0, 0);
      acc[3] = __builtin_amdgcn_mfma_f32_32x32x16_f16(a, __builtin_bit_cast(f16x8, Braw[3][16 + qx]), acc[3], 0, 0, 0);
    }
    // ---- 16 h chunks, rolling 4-deep prefetch, A straight from registers ----
#pragma unroll
    for (int q = 0; q < 16; ++q) {
      f16x8 a = __builtin_bit_cast(f16x8, ah[q & 3]);
      if (q + 4 < 16)
        ah[q & 3] = load_frag(hrd + fragbase + (unsigned)(q + 4) * 1024u);
      acc[0] = __builtin_amdgcn_mfma_f32_32x32x16_f16(a, __builtin_bit_cast(f16x8, Braw[0][q]), acc[0], 0, 0, 0);
      acc[1] = __builtin_amdgcn_mfma_f32_32x32x16_f16(a, __builtin_bit_cast(f16x8, Braw[1][q]), acc[1], 0, 0, 0);
      acc[2] = __builtin_amdgcn_mfma_f32_32x32x16_f16(a, __builtin_bit_cast(f16x8, Braw[2][q]), acc[2], 0, 0, 0);
      acc[3] = __builtin_amdgcn_mfma_f32_32x32x16_f16(a, __builtin_bit_cast(f16x8, Braw[3][q]), acc[3], 0, 0, 0);
    }

    // ---- cross-wave K reduction (64KB LDS) ----
#pragma unroll
    for (int n = 0; n < 4; ++n) {
#pragma unroll
      for (int c = 0; c < 4; ++c) {
        float4 v;
        v.x = acc[n][4 * c + 0]; v.y = acc[n][4 * c + 1];
        v.z = acc[n][4 * c + 2]; v.w = acc[n][4 * c + 3];
        redv[((w * 4u + (unsigned)n) * 4u + (unsigned)c) * 64u + l] = v;
      }
    }
    __syncthreads();  // (A) reduce buffer complete

    float gv[4][4];
#pragma unroll
    for (int n = 0; n < 4; ++n) {
      float4 s; s.x = bias_v[n]; s.y = bias_v[n]; s.z = bias_v[n]; s.w = bias_v[n];
#pragma unroll
      for (int wo = 0; wo < 4; ++wo) {
        float4 v = redv[(((unsigned)wo * 4u + (unsigned)n) * 4u + w) * 64u + l];
        s.x += v.x; s.y += v.y; s.z += v.z; s.w += v.w;
      }
      gv[n][0] = s.x; gv[n][1] = s.y; gv[n][2] = s.z; gv[n][3] = s.w;
    }

    // ---- per-lane LSTM cell update (rows 8w+i+4hi); stage h to LDS ----
    const bool last = (t == 255u);
#pragma unroll
    for (int i = 0; i < 4; ++i) {
      float ig = fast_sig(gv[0][i]);
      float fg = fast_sig(gv[1][i]);
      float gg = fast_tanh(gv[2][i]);
      float og = fast_sig(gv[3][i]);
      float cc = fg * c_st[i] + ig * gg;
      c_st[i] = cc;
      float hh = og * fast_tanh(cc);
      hst[(8u * w + (unsigned)i + 4u * hi) * 32u + lo5] = f2h(hh);
      if (last) sigh[soff[i]] = fast_sig(hh);
    }

    if (!last) {
      __syncthreads();  // (B) hst tile complete
      // ---- producer fragment write: 256 x 8B coalesced agent stores ----
      {
        u64 v = *(const u64*)((const char*)hst + hst_rd);
        __hip_atomic_store((u64*)(hwr + pw_off), v, __ATOMIC_RELAXED, SCOPE_AGENT);
      }
      // prefetch next step's x fragments
      xb += 65536u;
      xr[0] = *(const int4*)(xbase + xb);
      xr[1] = *(const int4*)(xbase + xb + 32u);
      // (C) barrier lowering waits vmcnt(0): all h stores ACKed at MALL
      __syncthreads();
      if (tid == 0)
        __hip_atomic_store(&flags[cg], t + 1u, __ATOMIC_RELAXED, SCOPE_AGENT);
      // ---- per-wave poll: only this wave's 8 producers (cg' in [8w,8w+8)) ----
      {
        const unsigned tgt = t + 1u;
        const unsigned fidx = w * 8u + (l & 7u);
        for (;;) {
          unsigned f = __hip_atomic_load(&flags[fidx], __ATOMIC_RELAXED, SCOPE_AGENT);
          if (__all(f >= tgt)) break;
          __builtin_amdgcn_s_sleep(1);
        }
      }
      // no trailing barrier: waves proceed independently; skew absorbed at (A)
    }
  }
}

// out[b][o] = b_fc[o] + sum_k sigh[b][k] * W_fc[o][k]
__global__ void final_fc(const float* __restrict__ sigh, const float* __restrict__ W_fc,
                         const float* __restrict__ b_fc, float* __restrict__ out) {
  unsigned b = blockIdx.x;
  unsigned o = threadIdx.x;
  const float* hrow = sigh + (size_t)b * 1024u;
  const float* wrow = W_fc + (size_t)o * 1024u;
  float acc = b_fc[o];
#pragma unroll 8
  for (unsigned k = 0; k < 1024u; k += 4u) {
    float4 hv = *(const float4*)(hrow + k);
    float4 wv = *(const float4*)(wrow + k);
    acc += hv.x * wv.x + hv.y * wv.y + hv.z * wv.z + hv.w * wv.w;
  }
  out[b * 128u + o] = acc;
}

extern "C" void kernel_launch(void* const* d_in, const int* in_sizes, int n_in,
                              void* d_out, int out_size, void* d_ws, size_t ws_size,
                              hipStream_t stream) {
  (void)in_sizes; (void)n_in; (void)out_size; (void)ws_size;
  const float* x    = (const float*)d_in[0];
  const float* h0   = (const float*)d_in[1];
  const float* c0   = (const float*)d_in[2];
  const float* W_ih = (const float*)d_in[3];
  const float* W_hh = (const float*)d_in[4];
  const float* b_ih = (const float*)d_in[5];
  const float* b_hh = (const float*)d_in[6];
  const float* W_fc = (const float*)d_in[7];
  const float* b_fc = (const float*)d_in[8];

  char* ws = (char*)d_ws;
  unsigned short* wp   = (unsigned short*)(ws + WS_WP);
  float*          bias = (float*)(ws + WS_BIAS);
  unsigned short* xT   = (unsigned short*)(ws + WS_XT);
  unsigned short* hb   = (unsigned short*)(ws + WS_HB);
  float*          sigh = (float*)(ws + WS_SIGH);
  unsigned*       bar  = (unsigned*)(ws + WS_BAR);
  float*          out  = (float*)d_out;

  prep_pack<<<18432, 256, 0, stream>>>(W_ih, W_hh, b_ih, b_hh, wp, bias);
  prep_misc<<<32768, 256, 0, stream>>>(x, h0, xT, hb, bar);
  lstm_main<<<256, 256, 67584, stream>>>(wp, bias, xT, hb, c0, sigh, bar);
  final_fc<<<256, 128, 0, stream>>>(sigh, W_fc, b_fc, out);
}

// Round 11
// 1729.597 us; speedup vs baseline: 1.0001x; 1.0001x over previous
//
#include <hip/hip_runtime.h>

// LSTM (B=256, T=256, F=128, H=1024) + sigmoid + FC(1024->128).
// Persistent 256-WG x 256-thread kernel (4 waves, 1 wave/SIMD).
// Per step t: gates[32rows x 128cols] = [h|x](fp16) x W_cat^T(fp16, register-
// resident) + bias; per-lane i,f,g,o -> c,h update (fp32).
//
// R11 = R10 fragment-layout exchange + R8 full-depth MLP:
// h lives at the MALL in MFMA A-FRAGMENT LAYOUT (agent-scope relaxed atomics):
//   hb[buf][rg][chunk 0..63][lane 0..63][16B], chunk = 16 k-cols x 32 rows:
//   byte(chunk,l,j) = h[row=l&31][col = chunk*16 + (l>>5)*8 + j]
// Consumers preload ALL 16 chunks to registers up front (32 coalesced u64
// agent loads, 16KB/wave in flight = R8's MLP; R10's rolling-4 window exposed
// ~400cy of MALL latency per chunk and regressed). x-chunk MFMAs issue while
// h loads fly; 16 h-chunk MFMA groups then run from registers with per-use
// vmcnt waits pipelining in completion order. No LDS stage round trip.
// Producers write their 32x32 tile as 2 contiguous 1KB chunks: 256 threads x
// one coalesced 8B agent store, sourced from the 2KB hst LDS tile.
// Wave w consumes h chunks [16w,16w+16) (K [w*256,+256)) + x-K [w*32,+32).
// Reduce: 4-wave, 64KB LDS. Cell: 4 rows/thread.
// Barrier: RMW-free epoch flags; wave w polls its 8 producers cg' in
// [8w,8w+8). 4 rotating h buffers; transitivity: flag[p]=t => p passed
// poll(t-2) => all 32 flags >= t-1 => all reads of h(t-3) done => writing
// hb[(t+1)&3] safe. Monotonic flags, replay-safe.
// MFMA mfma_f32_32x32x16_f16: A lane row=l&31,k=(l>>5)*8+j; B col=l&31,
// same k; C col=l&31, row=(reg&3)+8*(reg>>2)+4*(l>>5) [m101].

typedef _Float16 f16x8 __attribute__((ext_vector_type(8)));
typedef float f32x16 __attribute__((ext_vector_type(16)));
typedef unsigned long long u64;
struct U128 { u64 a, b; };

#define SCOPE_AGENT __HIP_MEMORY_SCOPE_AGENT

#define WS_WP    0ull
#define WS_BIAS  9437184ull
#define WS_XT    (WS_BIAS + 16384ull)
#define WS_HB    (WS_XT + 16777216ull)          // 4 buffers x 524288B
#define WS_SIGH  (WS_HB + 4ull * 524288ull)
#define WS_BAR   (WS_SIGH + 1048576ull)

__device__ __forceinline__ unsigned short f2h(float f) {
  _Float16 h = (_Float16)f;
  return __builtin_bit_cast(unsigned short, h);
}

__device__ __forceinline__ float fast_sig(float x) {
  return __builtin_amdgcn_rcpf(1.f + __expf(-x));
}
__device__ __forceinline__ float fast_tanh(float x) {
  return __builtin_fmaf(2.f, fast_sig(2.f * x), -1.f);
}

// Agent-coherent 16B fragment load (two u64 relaxed atomics -> MALL).
__device__ __forceinline__ int4 load_frag(const char* p) {
  U128 u;
  u.a = __hip_atomic_load((const u64*)p,       __ATOMIC_RELAXED, SCOPE_AGENT);
  u.b = __hip_atomic_load((const u64*)(p + 8), __ATOMIC_RELAXED, SCOPE_AGENT);
  return __builtin_bit_cast(int4, u);
}

// Pack W_cat[4096][1152] (fp16) into per-(cg,wave,n,q,lane) MFMA B-fragments.
// flat idx i = ((((cg*4 + w)*4 + n)*18 + q)*64 + l)*8 + j
//   gcol = n*1024 + cg*32 + (l&31); khi = (l>>5)*8 + j
//   q<16:  k = w*256 + q*16 + khi  (h region, W_hh[gcol][k])
//   q>=16: f = w*32 + (q-16)*16 + khi  (x region, W_ih[gcol][f])
__global__ void prep_pack(const float* __restrict__ W_ih, const float* __restrict__ W_hh,
                          const float* __restrict__ b_ih, const float* __restrict__ b_hh,
                          unsigned short* __restrict__ wp, float* __restrict__ bias) {
  unsigned i = blockIdx.x * 256u + threadIdx.x;
  if (i < 4718592u) {
    unsigned j = i & 7u;
    unsigned l = (i >> 3) & 63u;
    unsigned rest = i >> 9;
    unsigned q = rest % 18u;
    unsigned rest2 = rest / 18u;
    unsigned n = rest2 & 3u;
    unsigned rest3 = rest2 >> 2;
    unsigned w = rest3 & 3u;
    unsigned cg = rest3 >> 2;
    unsigned gcol = n * 1024u + cg * 32u + (l & 31u);
    unsigned khi = (l >> 5) * 8u + j;
    float v;
    if (q < 16u) {
      unsigned k = w * 256u + q * 16u + khi;
      v = W_hh[(size_t)gcol * 1024u + k];
    } else {
      unsigned k = w * 32u + (q - 16u) * 16u + khi;
      v = W_ih[(size_t)gcol * 128u + k];
    }
    wp[i] = f2h(v);
  }
  if (i < 4096u) bias[i] = b_ih[i] + b_hh[i];
}

// x[B][T][F] fp32 -> xT[T][B][F] fp16 ; h0 -> hb buffer 0 in FRAGMENT layout;
// zero flags.
__global__ void prep_misc(const float* __restrict__ x, const float* __restrict__ h0,
                          unsigned short* __restrict__ xT, unsigned short* __restrict__ hb0,
                          unsigned* __restrict__ bar) {
  unsigned i = blockIdx.x * 256u + threadIdx.x;
  if (i < 8388608u) {
    unsigned f = i & 127u;
    unsigned b = (i >> 7) & 255u;
    unsigned t = i >> 15;
    xT[i] = f2h(x[((size_t)b * 256u + t) * 128u + f]);
  }
  if (i < 262144u) {
    // hb0[rg][chunk][l][j] = h0[rg*32 + (l&31)][chunk*16 + (l>>5)*8 + j]
    unsigned j = i & 7u;
    unsigned l = (i >> 3) & 63u;
    unsigned chunk = (i >> 9) & 63u;
    unsigned rg = i >> 15;
    unsigned row = rg * 32u + (l & 31u);
    unsigned col = chunk * 16u + (l >> 5) * 8u + j;
    hb0[i] = f2h(h0[row * 1024u + col]);
  }
  if (i < 768u) bar[i] = 0u;
}

__launch_bounds__(256, 1)
__global__ void lstm_main(const unsigned short* __restrict__ wp,
                          const float* __restrict__ bias,
                          const unsigned short* __restrict__ xT,
                          unsigned short* __restrict__ hb,
                          const float* __restrict__ c0,
                          float* __restrict__ sigh,
                          unsigned* __restrict__ bar) {
  extern __shared__ char lds[];
  float4* redv = (float4*)lds;                            // 64 KB reduce
  unsigned short* hst = (unsigned short*)(lds + 65536);   // 2 KB h tile

  const unsigned tid = threadIdx.x;
  const unsigned wg  = blockIdx.x;
  const unsigned w   = tid >> 6;       // wave 0..3 (K-slice owner)
  const unsigned l   = tid & 63u;
  const unsigned rg  = wg >> 5;        // 0..7  cohort (32 rows)
  const unsigned cg  = wg & 31u;       // 0..31 col group (32 cols)
  const unsigned lo5 = l & 31u;
  const unsigned hi  = l >> 5;

  // ---- register-resident W fragments (72 x int4) ----
  int4 Braw[4][18];
  {
    const int4* wpv = (const int4*)wp;
    const unsigned wbase = (cg * 4u + w) * 4608u;
#pragma unroll
    for (int n = 0; n < 4; ++n) {
#pragma unroll
      for (int q = 0; q < 18; ++q) {
        Braw[n][q] = wpv[wbase + (unsigned)(n * 18 + q) * 64u + l];
      }
    }
  }

  float bias_v[4];
#pragma unroll
  for (int n = 0; n < 4; ++n) bias_v[n] = bias[(unsigned)n * 1024u + cg * 32u + lo5];

  // cell rows r = rg*32 + 8w + i + 4*hi, col = cg*32 + lo5
  const unsigned col = cg * 32u + lo5;
  float c_st[4];
  unsigned soff[4];
#pragma unroll
  for (int i = 0; i < 4; ++i) {
    unsigned r = rg * 32u + 8u * w + (unsigned)i + 4u * hi;
    soff[i] = r * 1024u + col;
    c_st[i] = c0[soff[i]];
  }

  // consumer fragment addressing: wave w reads chunks 16w..16w+15
  const unsigned fragbase = rg * 65536u + (w * 16u) * 1024u + l * 16u;
  // x: lane l -> row rg*32+(l&31), f = w*32 + hi*8 ; +65536/step
  unsigned xb = ((rg * 32u + lo5) * 128u + w * 32u + hi * 8u) * 2u;

  const char* xbase = (const char*)xT;
  const char* hbase = (const char*)hb;
  unsigned* flags = &bar[rg * 32u];    // 32 epoch flags, one 128B line

  // producer fragment write: 256 threads x 8B coalesced
  const unsigned pq = tid >> 7;
  const unsigned pl = (tid >> 1) & 63u;
  const unsigned pp = tid & 1u;
  const unsigned plc = pq * 16u + (pl >> 5) * 8u + pp * 4u;   // local col
  const unsigned hst_rd = (pl & 31u) * 64u + plc * 2u;        // byte in hst
  const unsigned pw_off = rg * 65536u + (cg * 2u + pq) * 1024u + pl * 16u + pp * 8u;

  int4 xr[2];
  xr[0] = *(const int4*)(xbase + xb);
  xr[1] = *(const int4*)(xbase + xb + 32u);

  for (unsigned t = 0; t < 256u; ++t) {
    const char* hrd = hbase + ((t & 3u) * 524288u);
    char* hwr = (char*)hbase + (((t + 1u) & 3u) * 524288u);

    // ---- preload ALL 16 h fragment chunks (32 coalesced u64 loads in flight,
    //      16KB/wave MLP: one MALL latency exposure, R8-style) ----
    int4 ah[16];
#pragma unroll
    for (int q = 0; q < 16; ++q)
      ah[q] = load_frag(hrd + fragbase + (unsigned)q * 1024u);

    f32x16 acc[4] = {};
    // x chunks (q=16,17) while h loads are in flight
#pragma unroll
    for (int qx = 0; qx < 2; ++qx) {
      f16x8 a = __builtin_bit_cast(f16x8, xr[qx]);
      acc[0] = __builtin_amdgcn_mfma_f32_32x32x16_f16(a, __builtin_bit_cast(f16x8, Braw[0][16 + qx]), acc[0], 0, 0, 0);
      acc[1] = __builtin_amdgcn_mfma_f32_32x32x16_f16(a, __builtin_bit_cast(f16x8, Braw[1][16 + qx]), acc[1], 0, 0, 0);
      acc[2] = __builtin_amdgcn_mfma_f32_32x32x16_f16(a, __builtin_bit_cast(f16x8, Braw[2][16 + qx]), acc[2], 0, 0, 0);
      acc[3] = __builtin_amdgcn_mfma_f32_32x32x16_f16(a, __builtin_bit_cast(f16x8, Braw[3][16 + qx]), acc[3], 0, 0, 0);
    }
    // ---- 16 h chunks straight from registers (per-use vmcnt pipelining) ----
#pragma unroll
    for (int q = 0; q < 16; ++q) {
      f16x8 a = __builtin_bit_cast(f16x8, ah[q]);
      acc[0] = __builtin_amdgcn_mfma_f32_32x32x16_f16(a, __builtin_bit_cast(f16x8, Braw[0][q]), acc[0], 0, 0, 0);
      acc[1] = __builtin_amdgcn_mfma_f32_32x32x16_f16(a, __builtin_bit_cast(f16x8, Braw[1][q]), acc[1], 0, 0, 0);
      acc[2] = __builtin_amdgcn_mfma_f32_32x32x16_f16(a, __builtin_bit_cast(f16x8, Braw[2][q]), acc[2], 0, 0, 0);
      acc[3] = __builtin_amdgcn_mfma_f32_32x32x16_f16(a, __builtin_bit_cast(f16x8, Braw[3][q]), acc[3], 0, 0, 0);
    }

    // ---- cross-wave K reduction (64KB LDS) ----
#pragma unroll
    for (int n = 0; n < 4; ++n) {
#pragma unroll
      for (int c = 0; c < 4; ++c) {
        float4 v;
        v.x = acc[n][4 * c + 0]; v.y = acc[n][4 * c + 1];
        v.z = acc[n][4 * c + 2]; v.w = acc[n][4 * c + 3];
        redv[((w * 4u + (unsigned)n) * 4u + (unsigned)c) * 64u + l] = v;
      }
    }
    __syncthreads();  // (A) reduce buffer complete

    float gv[4][4];
#pragma unroll
    for (int n = 0; n < 4; ++n) {
      float4 s; s.x = bias_v[n]; s.y = bias_v[n]; s.z = bias_v[n]; s.w = bias_v[n];
#pragma unroll
      for (int wo = 0; wo < 4; ++wo) {
        float4 v = redv[(((unsigned)wo * 4u + (unsigned)n) * 4u + w) * 64u + l];
        s.x += v.x; s.y += v.y; s.z += v.z; s.w += v.w;
      }
      gv[n][0] = s.x; gv[n][1] = s.y; gv[n][2] = s.z; gv[n][3] = s.w;
    }

    // ---- per-lane LSTM cell update (rows 8w+i+4hi); stage h to LDS ----
    const bool last = (t == 255u);
#pragma unroll
    for (int i = 0; i < 4; ++i) {
      float ig = fast_sig(gv[0][i]);
      float fg = fast_sig(gv[1][i]);
      float gg = fast_tanh(gv[2][i]);
      float og = fast_sig(gv[3][i]);
      float cc = fg * c_st[i] + ig * gg;
      c_st[i] = cc;
      float hh = og * fast_tanh(cc);
      hst[(8u * w + (unsigned)i + 4u * hi) * 32u + lo5] = f2h(hh);
      if (last) sigh[soff[i]] = fast_sig(hh);
    }

    if (!last) {
      __syncthreads();  // (B) hst tile complete
      // ---- producer fragment write: 256 x 8B coalesced agent stores ----
      {
        u64 v = *(const u64*)((const char*)hst + hst_rd);
        __hip_atomic_store((u64*)(hwr + pw_off), v, __ATOMIC_RELAXED, SCOPE_AGENT);
      }
      // prefetch next step's x fragments
      xb += 65536u;
      xr[0] = *(const int4*)(xbase + xb);
      xr[1] = *(const int4*)(xbase + xb + 32u);
      // (C) barrier lowering waits vmcnt(0): all h stores ACKed at MALL
      __syncthreads();
      if (tid == 0)
        __hip_atomic_store(&flags[cg], t + 1u, __ATOMIC_RELAXED, SCOPE_AGENT);
      // ---- per-wave poll: only this wave's 8 producers (cg' in [8w,8w+8)) ----
      {
        const unsigned tgt = t + 1u;
        const unsigned fidx = w * 8u + (l & 7u);
        for (;;) {
          unsigned f = __hip_atomic_load(&flags[fidx], __ATOMIC_RELAXED, SCOPE_AGENT);
          if (__all(f >= tgt)) break;
          __builtin_amdgcn_s_sleep(1);
        }
      }
      // no trailing barrier: waves proceed independently; skew absorbed at (A)
    }
  }
}

// out[b][o] = b_fc[o] + sum_k sigh[b][k] * W_fc[o][k]
__global__ void final_fc(const float* __restrict__ sigh, const float* __restrict__ W_fc,
                         const float* __restrict__ b_fc, float* __restrict__ out) {
  unsigned b = blockIdx.x;
  unsigned o = threadIdx.x;
  const float* hrow = sigh + (size_t)b * 1024u;
  const float* wrow = W_fc + (size_t)o * 1024u;
  float acc = b_fc[o];
#pragma unroll 8
  for (unsigned k = 0; k < 1024u; k += 4u) {
    float4 hv = *(const float4*)(hrow + k);
    float4 wv = *(const float4*)(wrow + k);
    acc += hv.x * wv.x + hv.y * wv.y + hv.z * wv.z + hv.w * wv.w;
  }
  out[b * 128u + o] = acc;
}

extern "C" void kernel_launch(void* const* d_in, const int* in_sizes, int n_in,
                              void* d_out, int out_size, void* d_ws, size_t ws_size,
                              hipStream_t stream) {
  (void)in_sizes; (void)n_in; (void)out_size; (void)ws_size;
  const float* x    = (const float*)d_in[0];
  const float* h0   = (const float*)d_in[1];
  const float* c0   = (const float*)d_in[2];
  const float* W_ih = (const float*)d_in[3];
  const float* W_hh = (const float*)d_in[4];
  const float* b_ih = (const float*)d_in[5];
  const float* b_hh = (const float*)d_in[6];
  const float* W_fc = (const float*)d_in[7];
  const float* b_fc = (const float*)d_in[8];

  char* ws = (char*)d_ws;
  unsigned short* wp   = (unsigned short*)(ws + WS_WP);
  float*          bias = (float*)(ws + WS_BIAS);
  unsigned short* xT   = (unsigned short*)(ws + WS_XT);
  unsigned short* hb   = (unsigned short*)(ws + WS_HB);
  float*          sigh = (float*)(ws + WS_SIGH);
  unsigned*       bar  = (unsigned*)(ws + WS_BAR);
  float*          out  = (float*)d_out;

  prep_pack<<<18432, 256, 0, stream>>>(W_ih, W_hh, b_ih, b_hh, wp, bias);
  prep_misc<<<32768, 256, 0, stream>>>(x, h0, xT, hb, bar);
  lstm_main<<<256, 256, 67584, stream>>>(wp, bias, xT, hb, c0, sigh, bar);
  final_fc<<<256, 128, 0, stream>>>(sigh, W_fc, b_fc, out);
}

// Round 12
// 1307.938 us; speedup vs baseline: 1.3225x; 1.3224x over previous
//
#include <hip/hip_runtime.h>

// LSTM (B=256, T=256, F=128, H=1024) + sigmoid + FC(1024->128).
// Persistent 256-WG x 256-thread kernel (4 waves, 1 wave/SIMD).
// R12 = R8 structure + FP8 h exchange (W stays fp16 -> no W quant error).
// Theory: the cohort h broadcast (16 MB/step) is MALL-bandwidth-bound on the
// agent-scope bypass path; halving bytes is the only remaining lever.
//
// h code (8-bit, self-consistent): byte = sign | f16bits(v/256)[13:7], RNE via
// f16 rounding. Decode: f16bits = ((b&0x80)<<8)|((b&0x7f)<<7), worth v/256.
// The x256 is FOLDED into W (wp = 256*W, exact pow2) and xT = x/256, so both
// h and x contributions equal v*W with no extra multiplies in the hot loop.
// Dequant pairing emits A elements in byte order {0,2,1,3,4,6,5,7}; prep_pack
// applies the same k-permutation for h chunks -> dot products invariant.
//
// Per step: stage own 8KB fp8 K-slice coalesced (16 u64 agent loads from
// MALL), write to private LDS region (XOR-swizzled), dequant+MFMA 16 h chunks
// + 2 fp16 x chunks; 4-wave K-reduce in LDS; cell update fp32; encode h fp8
// to 1KB hst tile; 256x4B coalesced agent stores; RMW-free epoch flags with
// per-wave poll of 8 producers; 4 rotating h buffers (WAR transitivity:
// flag[p]=t => p passed poll(t-2) => all flags >= t-1 => h(t-3) reads done).
// MFMA mfma_f32_32x32x16_f16: A lane row=l&31,k=(l>>5)*8+j; C col=l&31,
// row=(reg&3)+8*(reg>>2)+4*(l>>5) [m101].

typedef _Float16 f16x8 __attribute__((ext_vector_type(8)));
typedef float f32x16 __attribute__((ext_vector_type(16)));
typedef unsigned long long u64;

#define SCOPE_AGENT __HIP_MEMORY_SCOPE_AGENT

#define WS_WP    0ull
#define WS_BIAS  9437184ull
#define WS_XT    (WS_BIAS + 16384ull)
#define WS_HB    (WS_XT + 16777216ull)          // 4 buffers x 262144B (fp8)
#define WS_SIGH  (WS_HB + 4ull * 262144ull)
#define WS_BAR   (WS_SIGH + 1048576ull)

__device__ __forceinline__ unsigned short f2h(float f) {
  _Float16 h = (_Float16)f;
  return __builtin_bit_cast(unsigned short, h);
}

__device__ __forceinline__ float fast_sig(float x) {
  return __builtin_amdgcn_rcpf(1.f + __expf(-x));
}
__device__ __forceinline__ float fast_tanh(float x) {
  return __builtin_fmaf(2.f, fast_sig(2.f * x), -1.f);
}

// h fp8 encode: v in (-1,1) -> byte = sign | RNE(f16bits(v/256))[13:7]
__device__ __forceinline__ unsigned char h_enc(float v) {
  _Float16 gh = (_Float16)(v * 0.00390625f);
  unsigned m = __builtin_bit_cast(unsigned short, gh);
  unsigned r = m + 0x3fu + ((m >> 7) & 1u);
  return (unsigned char)(((m >> 8) & 0x80u) | ((r >> 7) & 0x7fu));
}

// dequant 8 fp8 bytes -> f16x8 patterns worth v/256, element order
// {b0,b2,b1,b3,b4,b6,b5,b7} (prep_pack permutes W's k the same way).
__device__ __forceinline__ f16x8 dq(u64 v) {
  unsigned w0 = (unsigned)v, w1 = (unsigned)(v >> 32);
  unsigned e0 = w0 & 0x00ff00ffu, o0 = (w0 >> 8) & 0x00ff00ffu;
  unsigned e1 = w1 & 0x00ff00ffu, o1 = (w1 >> 8) & 0x00ff00ffu;
  int4 t;
  t.x = (int)((e0 + (e0 & 0x00800080u)) << 7);
  t.y = (int)((o0 + (o0 & 0x00800080u)) << 7);
  t.z = (int)((e1 + (e1 & 0x00800080u)) << 7);
  t.w = (int)((o1 + (o1 & 0x00800080u)) << 7);
  return __builtin_bit_cast(f16x8, t);
}

// Pack 256*W_cat into per-(cg,wave,n,q,lane) MFMA B-fragments (fp16).
// flat i = ((((cg*4 + w)*4 + n)*18 + q)*64 + l)*8 + j
//   gcol = n*1024 + cg*32 + (l&31); khi = (l>>5)*8
//   q<16 (h, PERMUTED j):  k = w*256 + q*16 + khi + P[j], P={0,2,1,3,4,6,5,7}
//   q>=16 (x, natural j):  f = w*32 + (q-16)*16 + khi + j
__global__ void prep_pack(const float* __restrict__ W_ih, const float* __restrict__ W_hh,
                          const float* __restrict__ b_ih, const float* __restrict__ b_hh,
                          unsigned short* __restrict__ wp, float* __restrict__ bias) {
  unsigned i = blockIdx.x * 256u + threadIdx.x;
  if (i < 4718592u) {
    unsigned j = i & 7u;
    unsigned l = (i >> 3) & 63u;
    unsigned rest = i >> 9;
    unsigned q = rest % 18u;
    unsigned rest2 = rest / 18u;
    unsigned n = rest2 & 3u;
    unsigned rest3 = rest2 >> 2;
    unsigned w = rest3 & 3u;
    unsigned cg = rest3 >> 2;
    unsigned gcol = n * 1024u + cg * 32u + (l & 31u);
    unsigned khi = (l >> 5) * 8u;
    float v;
    if (q < 16u) {
      unsigned pj = (0x75643120u >> (4u * j)) & 0xfu;   // {0,2,1,3,4,6,5,7}
      unsigned k = w * 256u + q * 16u + khi + pj;
      v = W_hh[(size_t)gcol * 1024u + k];
    } else {
      unsigned k = w * 32u + (q - 16u) * 16u + khi + j;
      v = W_ih[(size_t)gcol * 128u + k];
    }
    wp[i] = f2h(v * 256.0f);
  }
  if (i < 4096u) bias[i] = b_ih[i] + b_hh[i];
}

// x[B][T][F] fp32 -> xT[T][B][F] fp16 scaled by 1/256 ; h0 -> fp8 hb0 ;
// zero flags.
__global__ void prep_misc(const float* __restrict__ x, const float* __restrict__ h0,
                          unsigned short* __restrict__ xT, unsigned char* __restrict__ hb0,
                          unsigned* __restrict__ bar) {
  unsigned i = blockIdx.x * 256u + threadIdx.x;
  if (i < 8388608u) {
    unsigned f = i & 127u;
    unsigned b = (i >> 7) & 255u;
    unsigned t = i >> 15;
    xT[i] = f2h(x[((size_t)b * 256u + t) * 128u + f] * 0.00390625f);
  }
  if (i < 262144u) hb0[i] = h_enc(h0[i]);   // row-major [256][1024] fp8
  if (i < 768u) bar[i] = 0u;
}

__launch_bounds__(256, 1)
__global__ void lstm_main(const unsigned short* __restrict__ wp,
                          const float* __restrict__ bias,
                          const unsigned short* __restrict__ xT,
                          unsigned char* __restrict__ hb,
                          const float* __restrict__ c0,
                          float* __restrict__ sigh,
                          unsigned* __restrict__ bar) {
  extern __shared__ char lds[];
  // [0,32K): per-wave fp8 h stage, region w*8KB, [row][256B], XOR-swizzled
  // [32K,96K): f32 cross-wave reduce   [96K,+1K): fp8 hst tile
  char* stg = lds;
  float4* redv = (float4*)(lds + 32768);
  unsigned char* hst8 = (unsigned char*)(lds + 98304);

  const unsigned tid = threadIdx.x;
  const unsigned wg  = blockIdx.x;
  const unsigned w   = tid >> 6;       // wave 0..3 (K-slice owner)
  const unsigned l   = tid & 63u;
  const unsigned rg  = wg >> 5;        // 0..7  cohort (32 rows)
  const unsigned cg  = wg & 31u;       // 0..31 col group (32 cols)
  const unsigned lo5 = l & 31u;
  const unsigned hi  = l >> 5;

  // ---- register-resident W fragments (72 x int4) ----
  int4 Braw[4][18];
  {
    const int4* wpv = (const int4*)wp;
    const unsigned wbase = (cg * 4u + w) * 4608u;
#pragma unroll
    for (int n = 0; n < 4; ++n) {
#pragma unroll
      for (int q = 0; q < 18; ++q) {
        Braw[n][q] = wpv[wbase + (unsigned)(n * 18 + q) * 64u + l];
      }
    }
  }

  float bias_v[4];
#pragma unroll
  for (int n = 0; n < 4; ++n) bias_v[n] = bias[(unsigned)n * 1024u + cg * 32u + lo5];

  // cell rows r = rg*32 + 8w + i + 4*hi, col = cg*32 + lo5
  const unsigned col = cg * 32u + lo5;
  float c_st[4];
  unsigned soff[4];
#pragma unroll
  for (int i = 0; i < 4; ++i) {
    unsigned r = rg * 32u + 8u * w + (unsigned)i + 4u * hi;
    soff[i] = r * 1024u + col;
    c_st[i] = c0[soff[i]];
  }

  // stage: wave w loads rows (hi+2r), bytes [w*256 + lo5*8) of the fp8 tile
  const unsigned sgsrc0 = (rg * 32u + hi) * 1024u + w * 256u + lo5 * 8u;  // + r*2048
  const unsigned sdst0  = w * 8192u + hi * 256u + lo5 * 8u;               // + r*512
  // frag read: region w, row lo5, byte q*16 + hi*8; XOR by (row&7)<<3
  const unsigned frb = w * 8192u + lo5 * 256u + hi * 8u;
  const unsigned fxr = (lo5 & 7u) << 3;

  unsigned xb = ((rg * 32u + lo5) * 128u + w * 32u + hi * 8u) * 2u;  // +65536/step

  const char* xbase = (const char*)xT;
  char* hbase = (char*)hb;
  unsigned* flags = &bar[rg * 32u];    // 32 epoch flags, one 128B line

  // producer store-out: 256 threads x 4B, row=tid>>3, 4-col seg=tid&7
  const unsigned srow = tid >> 3;
  const unsigned sseg = tid & 7u;
  const unsigned sgoff = (rg * 32u + srow) * 1024u + cg * 32u + sseg * 4u;

  int4 xr[2];
  xr[0] = *(const int4*)(xbase + xb);
  xr[1] = *(const int4*)(xbase + xb + 32u);

  for (unsigned t = 0; t < 256u; ++t) {
    const char* hrd = hbase + ((t & 3u) * 262144u);
    char* hwr = hbase + (((t + 1u) & 3u) * 262144u);

    // ---- per-wave coalesced fp8 stage loads (16 u64 agent loads -> MALL) ----
    u64 sa[16];
#pragma unroll
    for (int r = 0; r < 16; ++r)
      sa[r] = __hip_atomic_load((const u64*)(hrd + sgsrc0 + (unsigned)r * 2048u),
                                __ATOMIC_RELAXED, SCOPE_AGENT);

    f32x16 acc[4] = {};
    // x chunks (fp16, q=16,17) while stage loads are in flight
#pragma unroll
    for (int qx = 0; qx < 2; ++qx) {
      f16x8 a = __builtin_bit_cast(f16x8, xr[qx]);
      acc[0] = __builtin_amdgcn_mfma_f32_32x32x16_f16(a, __builtin_bit_cast(f16x8, Braw[0][16 + qx]), acc[0], 0, 0, 0);
      acc[1] = __builtin_amdgcn_mfma_f32_32x32x16_f16(a, __builtin_bit_cast(f16x8, Braw[1][16 + qx]), acc[1], 0, 0, 0);
      acc[2] = __builtin_amdgcn_mfma_f32_32x32x16_f16(a, __builtin_bit_cast(f16x8, Braw[2][16 + qx]), acc[2], 0, 0, 0);
      acc[3] = __builtin_amdgcn_mfma_f32_32x32x16_f16(a, __builtin_bit_cast(f16x8, Braw[3][16 + qx]), acc[3], 0, 0, 0);
    }

    // ---- write own slice to own LDS region (XOR swizzle by row&7) ----
#pragma unroll
    for (int r = 0; r < 16; ++r) {
      unsigned d = sdst0 + (unsigned)r * 512u;
      unsigned a = d ^ (((d >> 8) & 7u) << 3);
      *(u64*)(stg + a) = sa[r];
    }
    asm volatile("s_waitcnt lgkmcnt(0)" ::: "memory");

    // ---- 16 h chunks: ds_read_b64 + dequant + 4 MFMAs each ----
#pragma unroll
    for (int q = 0; q < 16; ++q) {
      unsigned a2 = (frb + (unsigned)q * 16u) ^ fxr;
      u64 hv = *(const u64*)(stg + a2);
      f16x8 a = dq(hv);
      acc[0] = __builtin_amdgcn_mfma_f32_32x32x16_f16(a, __builtin_bit_cast(f16x8, Braw[0][q]), acc[0], 0, 0, 0);
      acc[1] = __builtin_amdgcn_mfma_f32_32x32x16_f16(a, __builtin_bit_cast(f16x8, Braw[1][q]), acc[1], 0, 0, 0);
      acc[2] = __builtin_amdgcn_mfma_f32_32x32x16_f16(a, __builtin_bit_cast(f16x8, Braw[2][q]), acc[2], 0, 0, 0);
      acc[3] = __builtin_amdgcn_mfma_f32_32x32x16_f16(a, __builtin_bit_cast(f16x8, Braw[3][q]), acc[3], 0, 0, 0);
    }

    // ---- cross-wave K reduction (64KB LDS) ----
#pragma unroll
    for (int n = 0; n < 4; ++n) {
#pragma unroll
      for (int c = 0; c < 4; ++c) {
        float4 v;
        v.x = acc[n][4 * c + 0]; v.y = acc[n][4 * c + 1];
        v.z = acc[n][4 * c + 2]; v.w = acc[n][4 * c + 3];
        redv[((w * 4u + (unsigned)n) * 4u + (unsigned)c) * 64u + l] = v;
      }
    }
    __syncthreads();  // (A) reduce buffer complete

    float gv[4][4];
#pragma unroll
    for (int n = 0; n < 4; ++n) {
      float4 s; s.x = bias_v[n]; s.y = bias_v[n]; s.z = bias_v[n]; s.w = bias_v[n];
#pragma unroll
      for (int wo = 0; wo < 4; ++wo) {
        float4 v = redv[(((unsigned)wo * 4u + (unsigned)n) * 4u + w) * 64u + l];
        s.x += v.x; s.y += v.y; s.z += v.z; s.w += v.w;
      }
      gv[n][0] = s.x; gv[n][1] = s.y; gv[n][2] = s.z; gv[n][3] = s.w;
    }

    // ---- per-lane LSTM cell update (rows 8w+i+4hi); encode h fp8 to LDS ----
    const bool last = (t == 255u);
#pragma unroll
    for (int i = 0; i < 4; ++i) {
      float ig = fast_sig(gv[0][i]);
      float fg = fast_sig(gv[1][i]);
      float gg = fast_tanh(gv[2][i]);
      float og = fast_sig(gv[3][i]);
      float cc = fg * c_st[i] + ig * gg;
      c_st[i] = cc;
      float hh = og * fast_tanh(cc);
      hst8[(8u * w + (unsigned)i + 4u * hi) * 32u + lo5] = h_enc(hh);
      if (last) sigh[soff[i]] = fast_sig(hh);
    }

    if (!last) {
      __syncthreads();  // (B) hst tile complete
      // ---- producer store-out: 256 x 4B coalesced agent stores ----
      {
        unsigned v = *(const unsigned*)(hst8 + srow * 32u + sseg * 4u);
        __hip_atomic_store((unsigned*)(hwr + sgoff), v, __ATOMIC_RELAXED, SCOPE_AGENT);
      }
      // prefetch next step's x fragments
      xb += 65536u;
      xr[0] = *(const int4*)(xbase + xb);
      xr[1] = *(const int4*)(xbase + xb + 32u);
      // (C) barrier lowering waits vmcnt(0): all h stores ACKed at MALL
      __syncthreads();
      if (tid == 0)
        __hip_atomic_store(&flags[cg], t + 1u, __ATOMIC_RELAXED, SCOPE_AGENT);
      // ---- per-wave poll: only this wave's 8 producers (cg' in [8w,8w+8)) ----
      {
        const unsigned tgt = t + 1u;
        const unsigned fidx = w * 8u + (l & 7u);
        for (;;) {
          unsigned f = __hip_atomic_load(&flags[fidx], __ATOMIC_RELAXED, SCOPE_AGENT);
          if (__all(f >= tgt)) break;
          __builtin_amdgcn_s_sleep(1);
        }
      }
      // no trailing barrier: waves proceed independently; skew absorbed at (A)
    }
  }
}

// out[b][o] = b_fc[o] + sum_k sigh[b][k] * W_fc[o][k]
__global__ void final_fc(const float* __restrict__ sigh, const float* __restrict__ W_fc,
                         const float* __restrict__ b_fc, float* __restrict__ out) {
  unsigned b = blockIdx.x;
  unsigned o = threadIdx.x;
  const float* hrow = sigh + (size_t)b * 1024u;
  const float* wrow = W_fc + (size_t)o * 1024u;
  float acc = b_fc[o];
#pragma unroll 8
  for (unsigned k = 0; k < 1024u; k += 4u) {
    float4 hv = *(const float4*)(hrow + k);
    float4 wv = *(const float4*)(wrow + k);
    acc += hv.x * wv.x + hv.y * wv.y + hv.z * wv.z + hv.w * wv.w;
  }
  out[b * 128u + o] = acc;
}

extern "C" void kernel_launch(void* const* d_in, const int* in_sizes, int n_in,
                              void* d_out, int out_size, void* d_ws, size_t ws_size,
                              hipStream_t stream) {
  (void)in_sizes; (void)n_in; (void)out_size; (void)ws_size;
  const float* x    = (const float*)d_in[0];
  const float* h0   = (const float*)d_in[1];
  const float* c0   = (const float*)d_in[2];
  const float* W_ih = (const float*)d_in[3];
  const float* W_hh = (const float*)d_in[4];
  const float* b_ih = (const float*)d_in[5];
  const float* b_hh = (const float*)d_in[6];
  const float* W_fc = (const float*)d_in[7];
  const float* b_fc = (const float*)d_in[8];

  char* ws = (char*)d_ws;
  unsigned short* wp   = (unsigned short*)(ws + WS_WP);
  float*          bias = (float*)(ws + WS_BIAS);
  unsigned short* xT   = (unsigned short*)(ws + WS_XT);
  unsigned char*  hb   = (unsigned char*)(ws + WS_HB);
  float*          sigh = (float*)(ws + WS_SIGH);
  unsigned*       bar  = (unsigned*)(ws + WS_BAR);
  float*          out  = (float*)d_out;

  prep_pack<<<18432, 256, 0, stream>>>(W_ih, W_hh, b_ih, b_hh, wp, bias);
  prep_misc<<<32768, 256, 0, stream>>>(x, h0, xT, hb, bar);
  lstm_main<<<256, 256, 99328, stream>>>(wp, bias, xT, hb, c0, sigh, bar);
  final_fc<<<256, 128, 0, stream>>>(sigh, W_fc, b_fc, out);
}